// Round 2
// baseline (2408.012 us; speedup 1.0000x reference)
//
#include <hip/hip_runtime.h>
#include <hip/hip_bf16.h>
#include <math.h>

typedef __bf16 bf16x8 __attribute__((ext_vector_type(8)));
typedef float  f32x4  __attribute__((ext_vector_type(4)));

// Problem dims: B=8, U=32, L=64, H=512, V=32000, NSPK=16, R=4, E=128, S=2048
// N = B*U = 256 sequences, 4H = 2048 gate cols. All float I/O is fp32.

// Output element offsets (fp32 elements), flat order:
// enc_h, enc_c, memory_bank(S,B,H), lengths, mbu(S,B,H), lengths, hier(B,S)
#define OFF_ENCH 0
#define OFF_ENCC 4096
#define OFF_MB   8192
#define OFF_LEN1 8396800
#define OFF_MBU  8396808
#define OFF_LEN2 16785416
#define OFF_HIER 16785424

// Workspace byte offsets
#define WS_X     0          // X bf16: 16384*512*2 = 16777216
#define WS_WIH   16777216   // Wih bf16: 512*2048*2 = 2097152
#define WS_WHH   18874368   // Whh bf16: 2097152
#define WS_HBUF  20971520   // 2*256*512*2 = 524288
#define WS_CBUF  21495808   // 256*512*4   = 524288
#define WS_NODES 22020096   // 8*33*512*4  = 540672
#define WS_AGG   22560768   // 540672
#define WS_NEWN  23101440   // 540672 -> ends 23642112
#define WS_XG    23642112   // Xg bf16: 16384*2048*2 = 67108864 -> ends 90750976
#define WS_SPLIT_NEED 90750976ull
#define ZERO_WORDS 532480   // WS_HBUF..WS_NEWN start (h bufs, c, nodes, agg) in u32

__device__ __forceinline__ float sigm(float x) { return 1.0f / (1.0f + expf(-x)); }

// ---------------- init: zero state + constant outputs ----------------
__global__ __launch_bounds__(256) void k_init(unsigned int* zero_base,
                                              const int* lengths, float* out)
{
    int idx = blockIdx.x * 256 + threadIdx.x;
    if (idx < ZERO_WORDS) { zero_base[idx] = 0u; return; }
    int j = idx - ZERO_WORDS;
    if (j < 16384) { out[OFF_HIER + j] = 64.0f; return; }  // hier_matrix = L
    int j2 = j - 16384;
    if (j2 < 16) {
        float v = (float)lengths[j2 & 7];
        out[(j2 < 8 ? OFF_LEN1 : OFF_LEN2) + (j2 & 7)] = v;
    }
}

// ---------------- convert W_ih / W_hh fp32 -> bf16 ----------------
__global__ __launch_bounds__(256) void k_cvtw(const float* __restrict__ Wih,
                                              const float* __restrict__ Whh,
                                              __bf16* __restrict__ A,
                                              __bf16* __restrict__ Bf)
{
    int tid = blockIdx.x * 256 + threadIdx.x;   // 262144 threads
    const float* s = (tid >> 17) ? Whh : Wih;
    __bf16*      d = (tid >> 17) ? Bf  : A;
    int off = (tid & 131071) << 3;
    f32x4 v0 = *(const f32x4*)&s[off];
    f32x4 v1 = *(const f32x4*)&s[off + 4];
    bf16x8 o;
#pragma unroll
    for (int j = 0; j < 4; ++j) { o[j] = (__bf16)v0[j]; o[4 + j] = (__bf16)v1[j]; }
    *(bf16x8*)&d[off] = o;
}

// ---------------- embedding: X[t*256+n][k] = emb[word] + spk[spkid] (bf16) ----------------
__global__ __launch_bounds__(256) void k_embed(const int* __restrict__ src,
                                               const int* __restrict__ speaker,
                                               const float* __restrict__ emb,
                                               const float* __restrict__ spk,
                                               __bf16* __restrict__ X)
{
    int tid = blockIdx.x * 256 + threadIdx.x;   // 16384*64 threads
    int p  = tid >> 6;                          // t*256 + n
    int k8 = (tid & 63) << 3;
    int t = p >> 8, n = p & 255;
    int b = n >> 5, u = n & 31;
    int s = u * 64 + t;
    int word = src[s * 8 + b];                  // src (S,B,1)
    int sid  = speaker[b * 2048 + s];           // speaker (B,S)
    f32x4 e0 = *(const f32x4*)&emb[word * 512 + k8];
    f32x4 e1 = *(const f32x4*)&emb[word * 512 + k8 + 4];
    f32x4 s0 = *(const f32x4*)&spk[sid * 512 + k8];
    f32x4 s1 = *(const f32x4*)&spk[sid * 512 + k8 + 4];
    bf16x8 o;
#pragma unroll
    for (int j = 0; j < 4; ++j) {
        o[j]     = (__bf16)(e0[j] + s0[j]);
        o[4 + j] = (__bf16)(e1[j] + s1[j]);
    }
    *(bf16x8*)&X[p * 512 + k8] = o;
}

// ---------------- Xg = X @ W_ih + b_lstm  (M=16384,K=512,N=2048), bf16 out ----------------
__global__ __launch_bounds__(256) void k_gemm_xg(const __bf16* __restrict__ X,
                                                 const __bf16* __restrict__ Wih,
                                                 const float* __restrict__ bl,
                                                 __bf16* __restrict__ Xg)
{
    __shared__ __bf16 As[64][40];   // stride 40 elems = 80B (16B multiple, 2-way banks)
    __shared__ __bf16 Bs[64][40];   // B transposed: Bs[n][k]
    int tid = threadIdx.x;
    int w = tid >> 6, lane = tid & 63;
    int ml = lane & 15, q = lane >> 4;
    int m0 = blockIdx.y << 6, n0 = blockIdx.x << 6;
    f32x4 acc[4] = {};
    int ar = tid >> 2, ac = (tid & 3) << 3;     // A stage: 64 rows x 32 k
    int bk = tid >> 3, bj = (tid & 7) << 3;     // B stage: 32 k-rows x 64 cols
    for (int k0 = 0; k0 < 512; k0 += 32) {
        *(bf16x8*)&As[ar][ac] = *(const bf16x8*)&X[(m0 + ar) * 512 + k0 + ac];
        bf16x8 bv = *(const bf16x8*)&Wih[(k0 + bk) * 2048 + n0 + bj];
#pragma unroll
        for (int i = 0; i < 8; ++i) Bs[bj + i][bk] = bv[i];
        __syncthreads();
        bf16x8 a = *(const bf16x8*)&As[w * 16 + ml][q * 8];
#pragma unroll
        for (int ni = 0; ni < 4; ++ni) {
            bf16x8 bb = *(const bf16x8*)&Bs[ni * 16 + ml][q * 8];
            acc[ni] = __builtin_amdgcn_mfma_f32_16x16x32_bf16(a, bb, acc[ni], 0, 0, 0);
        }
        __syncthreads();
    }
#pragma unroll
    for (int ni = 0; ni < 4; ++ni) {
        int col = n0 + ni * 16 + ml;
        float bias = bl[col];
#pragma unroll
        for (int r = 0; r < 4; ++r) {
            int row = m0 + w * 16 + q * 4 + r;
            Xg[row * 2048 + col] = (__bf16)(acc[ni][r] + bias);
        }
    }
}

// ---------------- one LSTM step: gates GEMM + pointwise, fused ----------------
// Block (bx,by): rows n0..n0+63, h-cols j0..j0+31 across all 4 gates.
// split mode: gates = h@W_hh + Xg_t ; fused mode: gates = x_t@W_ih + h@W_hh + b
__global__ __launch_bounds__(256) void k_lstm_step(const __bf16* __restrict__ hin,
                                                   __bf16* __restrict__ hout,
                                                   float* __restrict__ cbuf,
                                                   const __bf16* __restrict__ Xt,
                                                   const __bf16* __restrict__ Wih,
                                                   const __bf16* __restrict__ Xg_t,
                                                   const __bf16* __restrict__ Whh,
                                                   const float* __restrict__ bl,
                                                   float* __restrict__ out,
                                                   int t, int fused)
{
    __shared__ __bf16 As[64][40];
    __shared__ __bf16 Bs[128][40];   // Bs[jj][k], jj -> gate g=jj>>5, col j0+(jj&31)
    int tid = threadIdx.x;
    int w = tid >> 6, lane = tid & 63;
    int ml = lane & 15, q = lane >> 4;
    int n0 = blockIdx.y << 6;
    int j0 = blockIdx.x << 5;
    f32x4 acc[8] = {};
    int ar = tid >> 2, ac = (tid & 3) << 3;
    int kmax = fused ? 1024 : 512;
    for (int k0 = 0; k0 < kmax; k0 += 32) {
        const __bf16* Ab; const __bf16* Bb; int kk0;
        if (fused && k0 < 512) { Ab = Xt;  Bb = Wih; kk0 = k0; }
        else                   { Ab = hin; Bb = Whh; kk0 = k0 & 511; }
        *(bf16x8*)&As[ar][ac] = *(const bf16x8*)&Ab[(n0 + ar) * 512 + kk0 + ac];
        for (int ch = tid; ch < 512; ch += 256) {      // 32 k-rows x 16 col-chunks
            int kk = ch >> 4, jj8 = (ch & 15) << 3;
            int col = (jj8 >> 5) * 512 + j0 + (jj8 & 31);
            bf16x8 bv = *(const bf16x8*)&Bb[(kk0 + kk) * 2048 + col];
#pragma unroll
            for (int i = 0; i < 8; ++i) Bs[jj8 + i][kk] = bv[i];
        }
        __syncthreads();
        bf16x8 a = *(const bf16x8*)&As[w * 16 + ml][q * 8];
#pragma unroll
        for (int ni = 0; ni < 8; ++ni) {
            bf16x8 bb = *(const bf16x8*)&Bs[ni * 16 + ml][q * 8];
            acc[ni] = __builtin_amdgcn_mfma_f32_16x16x32_bf16(a, bb, acc[ni], 0, 0, 0);
        }
        __syncthreads();
    }
    // Epilogue: lane holds 4 rows x 2 half-cols x 4 gates (frag ni = g*2 + h2)
#pragma unroll
    for (int r = 0; r < 4; ++r) {
        int n = n0 + w * 16 + q * 4 + r;
        int b = n >> 5, u = n & 31;
        int s = u * 64 + t;
#pragma unroll
        for (int h2 = 0; h2 < 2; ++h2) {
            int jc = j0 + h2 * 16 + ml;
            float pi, pf, pg, po;
            if (fused) {
                pi = acc[0 + h2][r] + bl[jc];
                pf = acc[2 + h2][r] + bl[512 + jc];
                pg = acc[4 + h2][r] + bl[1024 + jc];
                po = acc[6 + h2][r] + bl[1536 + jc];
            } else {
                pi = acc[0 + h2][r] + (float)Xg_t[n * 2048 + jc];
                pf = acc[2 + h2][r] + (float)Xg_t[n * 2048 + 512 + jc];
                pg = acc[4 + h2][r] + (float)Xg_t[n * 2048 + 1024 + jc];
                po = acc[6 + h2][r] + (float)Xg_t[n * 2048 + 1536 + jc];
            }
            float ig = sigm(pi), fg = sigm(pf);
            float gg = tanhf(pg), og = sigm(po);
            float cn = fg * cbuf[n * 512 + jc] + ig * gg;
            cbuf[n * 512 + jc] = cn;
            float hn = og * tanhf(cn);
            hout[n * 512 + jc] = (__bf16)hn;
            out[OFF_MB + (s * 8 + b) * 512 + jc] = hn;   // memory_bank[s][b][jc]
        }
    }
}

// ---------------- nodes: utt_h + global mean node ----------------
__global__ __launch_bounds__(256) void k_nodes(const __bf16* __restrict__ hT,
                                               float* __restrict__ nodes)
{
    int b = blockIdx.x;
    for (int k = threadIdx.x; k < 512; k += 256) {
        float sum = 0.f;
        for (int u = 0; u < 32; ++u) {
            float v = (float)hT[(b * 32 + u) * 512 + k];
            nodes[(b * 33 + u) * 512 + k] = v;
            sum += v;
        }
        nodes[(b * 33 + 32) * 512 + k] = sum * (1.0f / 32.0f);
    }
}

// ---------------- edges: msg = x_src @ W_rel[r], scatter-add to agg[dst] ----------------
__global__ __launch_bounds__(256) void k_edges(const float* __restrict__ nodes,
                                               const int* __restrict__ edge_src,
                                               const int* __restrict__ edge_dst,
                                               const int* __restrict__ rels,
                                               const float* __restrict__ Wrel,
                                               float* __restrict__ agg)
{
    __shared__ float xs[512];
    int eg = blockIdx.x;                 // B*E = 1024 blocks
    int b = eg >> 7, e = eg & 127;
    int es = edge_src[b * 128 + e];
    int ed = edge_dst[b * 128 + e];
    int r  = rels[b * 128 + e];
    int tid = threadIdx.x;
    for (int k = tid; k < 512; k += 256) xs[k] = nodes[(b * 33 + es) * 512 + k];
    __syncthreads();
    const float* Wr = Wrel + r * 262144;
    float a0 = 0.f, a1 = 0.f;
#pragma unroll 4
    for (int k = 0; k < 512; ++k) {
        float xk = xs[k];
        a0 += xk * Wr[k * 512 + tid];
        a1 += xk * Wr[k * 512 + 256 + tid];
    }
    atomicAdd(&agg[(b * 33 + ed) * 512 + tid], a0);
    atomicAdd(&agg[(b * 33 + ed) * 512 + 256 + tid], a1);
}

// ---------------- GNN gate fusion per node ----------------
__global__ __launch_bounds__(256) void k_gnn(const float* __restrict__ nodes,
                                             const float* __restrict__ agg,
                                             const float* __restrict__ Wself,
                                             const float* __restrict__ bgnn,
                                             const float* __restrict__ Wg1,
                                             const float* __restrict__ Wg2,
                                             float* __restrict__ newn,
                                             float* __restrict__ out)
{
    __shared__ float nd[512], ag[512];
    int vg = blockIdx.x;                 // B*33 = 264 blocks
    int b = vg / 33, v = vg % 33;
    int tid = threadIdx.x;
    for (int k = tid; k < 512; k += 256) {
        nd[k] = nodes[vg * 512 + k];
        ag[k] = agg[vg * 512 + k];
    }
    __syncthreads();
#pragma unroll
    for (int half = 0; half < 2; ++half) {
        int jj = tid + half * 256;
        float a_s = 0.f, a1 = 0.f, a2 = 0.f;
#pragma unroll 4
        for (int k = 0; k < 512; ++k) {
            float ndk = nd[k], agk = ag[k];
            a_s += ndk * Wself[k * 512 + jj];
            a1  += ndk * Wg1[k * 512 + jj];
            a2  += agk * Wg2[k * 512 + jj];
        }
        float outv = a_s + ag[jj] + bgnn[jj];
        outv = fmaxf(outv, 0.f);
        float gate = sigm(a1 + a2);
        float newv = gate * outv + (1.f - gate) * nd[jj];
        newn[vg * 512 + jj] = newv;
        if (v == 32) {                   // global_reps -> enc_h, enc_c
            out[OFF_ENCH + b * 512 + jj] = newv;
            out[OFF_ENCC + b * 512 + jj] = newv;
        }
    }
}

// ---------------- mbu: broadcast utt_upd over L into (S,B,H) ----------------
__global__ __launch_bounds__(256) void k_mbu(const float* __restrict__ newn,
                                             float* __restrict__ out)
{
    int idx = blockIdx.x * 256 + threadIdx.x;   // S*B*H/8 = 1048576 threads
    int k8 = (idx & 63) << 3;
    int rest = idx >> 6;
    int b = rest & 7;
    int s = rest >> 3;
    int u = s >> 6;
    const float* sp = &newn[(b * 33 + u) * 512 + k8];
    f32x4 v0 = *(const f32x4*)sp;
    f32x4 v1 = *(const f32x4*)(sp + 4);
    float* dp = &out[OFF_MBU + (s * 8 + b) * 512 + k8];
    *(f32x4*)dp = v0;
    *(f32x4*)(dp + 4) = v1;
}

extern "C" void kernel_launch(void* const* d_in, const int* in_sizes, int n_in,
                              void* d_out, int out_size, void* d_ws, size_t ws_size,
                              hipStream_t stream)
{
    (void)in_sizes; (void)n_in; (void)out_size;
    const int*   src      = (const int*)d_in[0];
    const int*   speaker  = (const int*)d_in[2];
    const int*   lengths  = (const int*)d_in[3];
    const int*   edge_src = (const int*)d_in[4];
    const int*   edge_dst = (const int*)d_in[5];
    const int*   rels     = (const int*)d_in[6];
    const float* emb   = (const float*)d_in[7];
    const float* spk   = (const float*)d_in[8];
    const float* Wih   = (const float*)d_in[9];
    const float* Whh   = (const float*)d_in[10];
    const float* bl    = (const float*)d_in[11];
    const float* Wrel  = (const float*)d_in[12];
    const float* Wself = (const float*)d_in[13];
    const float* bgnn  = (const float*)d_in[14];
    const float* Wg1   = (const float*)d_in[15];
    const float* Wg2   = (const float*)d_in[16];
    float* out = (float*)d_out;
    char*  ws  = (char*)d_ws;

    __bf16* X     = (__bf16*)(ws + WS_X);
    __bf16* WihB  = (__bf16*)(ws + WS_WIH);
    __bf16* WhhB  = (__bf16*)(ws + WS_WHH);
    __bf16* hb0   = (__bf16*)(ws + WS_HBUF);
    __bf16* hb1   = hb0 + 131072;
    float*  cbuf  = (float*)(ws + WS_CBUF);
    float*  nodes = (float*)(ws + WS_NODES);
    float*  agg   = (float*)(ws + WS_AGG);
    float*  newn  = (float*)(ws + WS_NEWN);
    __bf16* Xg    = (__bf16*)(ws + WS_XG);

    int split = (ws_size >= WS_SPLIT_NEED) ? 1 : 0;

    k_init<<<2145, 256, 0, stream>>>((unsigned int*)(ws + WS_HBUF), lengths, out);
    k_cvtw<<<1024, 256, 0, stream>>>(Wih, Whh, WihB, WhhB);
    k_embed<<<4096, 256, 0, stream>>>(src, speaker, emb, spk, X);
    if (split)
        k_gemm_xg<<<dim3(32, 256), 256, 0, stream>>>(X, WihB, bl, Xg);
    for (int t = 0; t < 64; ++t) {
        const __bf16* hin = (t & 1) ? hb1 : hb0;
        __bf16* hout      = (t & 1) ? hb0 : hb1;
        k_lstm_step<<<dim3(16, 4), 256, 0, stream>>>(
            hin, hout, cbuf,
            X + (size_t)t * 131072, WihB,
            Xg + (size_t)t * 524288, WhhB, bl,
            out, t, split ? 0 : 1);
    }
    k_nodes<<<8, 256, 0, stream>>>(hb0, nodes);   // after 64 steps, hT lives in hb0
    k_edges<<<1024, 256, 0, stream>>>(nodes, edge_src, edge_dst, rels, Wrel, agg);
    k_gnn<<<264, 256, 0, stream>>>(nodes, agg, Wself, bgnn, Wg1, Wg2, newn, out);
    k_mbu<<<4096, 256, 0, stream>>>(newn, out);
}

// Round 3
// 1352.047 us; speedup vs baseline: 1.7810x; 1.7810x over previous
//
#include <hip/hip_runtime.h>
#include <hip/hip_bf16.h>
#include <math.h>

typedef __bf16 bf16x8 __attribute__((ext_vector_type(8)));
typedef float  f32x4  __attribute__((ext_vector_type(4)));

// Problem dims: B=8, U=32, L=64, H=512, V=32000, NSPK=16, R=4, E=128, S=2048
// N = B*U = 256 sequences, 4H = 2048 gate cols. All float I/O is fp32.

// Output element offsets (fp32 elements), flat order:
// enc_h, enc_c, memory_bank(S,B,H), lengths, mbu(S,B,H), lengths, hier(B,S)
#define OFF_ENCH 0
#define OFF_ENCC 4096
#define OFF_MB   8192
#define OFF_LEN1 8396800
#define OFF_MBU  8396808
#define OFF_LEN2 16785416
#define OFF_HIER 16785424

// Workspace byte offsets
#define WS_X     0          // X bf16: 16384*512*2 = 16777216
#define WS_WIH   16777216   // WihT bf16 [2048][512]: 2097152
#define WS_WHH   18874368   // WhhT bf16 [2048][512]: 2097152
#define WS_HBUF  20971520   // 2*256*512*2 = 524288
#define WS_CBUF  21495808   // 256*512*4   = 524288
#define WS_NODES 22020096   // 8*33*512*4  = 540672
#define WS_AGG   22560768   // 540672
#define WS_NEWN  23101440   // 540672 -> ends 23642112
#define WS_XG    23642112   // Xg bf16: 16384*2048*2 = 67108864 -> ends 90750976
#define WS_SPLIT_NEED 90750976ull
#define ZERO_WORDS 532480   // WS_HBUF..WS_AGG end (h bufs, c, nodes, agg) in u32

__device__ __forceinline__ float sigm(float x) { return 1.0f / (1.0f + expf(-x)); }

__device__ __forceinline__ void async_cp16(const __bf16* g, __bf16* l) {
    __builtin_amdgcn_global_load_lds((const __attribute__((address_space(1))) void*)g,
                                     (__attribute__((address_space(3))) void*)l,
                                     16, 0, 0);
}

// ---------------- init: zero state + constant outputs ----------------
__global__ __launch_bounds__(256) void k_init(unsigned int* zero_base,
                                              const int* lengths, float* out)
{
    int idx = blockIdx.x * 256 + threadIdx.x;
    if (idx < ZERO_WORDS) { zero_base[idx] = 0u; return; }
    int j = idx - ZERO_WORDS;
    if (j < 16384) { out[OFF_HIER + j] = 64.0f; return; }  // hier_matrix = L
    int j2 = j - 16384;
    if (j2 < 16) {
        float v = (float)lengths[j2 & 7];
        out[(j2 < 8 ? OFF_LEN1 : OFF_LEN2) + (j2 & 7)] = v;
    }
}

// ---------------- W_ih / W_hh fp32 [512][2048] -> bf16 transposed [2048][512] ----------------
__global__ __launch_bounds__(256) void k_cvtw(const float* __restrict__ Wih,
                                              const float* __restrict__ Whh,
                                              __bf16* __restrict__ WihT,
                                              __bf16* __restrict__ WhhT)
{
    __shared__ float tile[64][65];
    int gid = blockIdx.x;                         // 512 blocks: 2 mats x 8 k x 32 c
    const float* Wsrc = (gid >> 8) ? Whh : Wih;
    __bf16*      Wdst = (gid >> 8) ? WhhT : WihT;
    int rem = gid & 255;
    int k0 = (rem >> 5) << 6;
    int c0 = (rem & 31) << 6;
    int tid = threadIdx.x;
#pragma unroll
    for (int i = 0; i < 16; ++i) {
        int idx = tid + i * 256;
        int kl = idx >> 6, cl = idx & 63;
        tile[cl][kl] = Wsrc[(size_t)(k0 + kl) * 2048 + c0 + cl];
    }
    __syncthreads();
#pragma unroll
    for (int i = 0; i < 16; ++i) {
        int idx = tid + i * 256;
        int cl = idx >> 6, kl = idx & 63;
        Wdst[(size_t)(c0 + cl) * 512 + k0 + kl] = (__bf16)tile[cl][kl];
    }
}

// ---------------- embedding: X[t*256+n][k] = emb[word] + spk[spkid] (bf16) ----------------
__global__ __launch_bounds__(256) void k_embed(const int* __restrict__ src,
                                               const int* __restrict__ speaker,
                                               const float* __restrict__ emb,
                                               const float* __restrict__ spk,
                                               __bf16* __restrict__ X)
{
    int tid = blockIdx.x * 256 + threadIdx.x;   // 16384*64 threads
    int p  = tid >> 6;                          // t*256 + n
    int k8 = (tid & 63) << 3;
    int t = p >> 8, n = p & 255;
    int b = n >> 5, u = n & 31;
    int s = u * 64 + t;
    int word = src[s * 8 + b];                  // src (S,B,1)
    int sid  = speaker[b * 2048 + s];           // speaker (B,S)
    f32x4 e0 = *(const f32x4*)&emb[word * 512 + k8];
    f32x4 e1 = *(const f32x4*)&emb[word * 512 + k8 + 4];
    f32x4 s0 = *(const f32x4*)&spk[sid * 512 + k8];
    f32x4 s1 = *(const f32x4*)&spk[sid * 512 + k8 + 4];
    bf16x8 o;
#pragma unroll
    for (int j = 0; j < 4; ++j) {
        o[j]     = (__bf16)(e0[j] + s0[j]);
        o[4 + j] = (__bf16)(e1[j] + s1[j]);
    }
    *(bf16x8*)&X[p * 512 + k8] = o;
}

// ---------------- Xg = X @ W_ih + b (M=16384,K=512,N=2048), m97-style 128x128 ----------------
// X[16384][512] row-major; WihT[2048][512] = B^T row-major; Xg bf16 [16384][2048]
__global__ __launch_bounds__(256) void k_gemm_xg(const __bf16* __restrict__ X,
                                                 const __bf16* __restrict__ Wt,
                                                 const float* __restrict__ bl,
                                                 __bf16* __restrict__ Xg)
{
    __shared__ __bf16 As[128 * 32];   // [row][k] stride 32, lane-contiguous for async cp
    __shared__ __bf16 Bs[128 * 32];   // [col][k] stride 32
    int tid = threadIdx.x;
    int w = tid >> 6, lane = tid & 63;
    int ml = lane & 15, q = lane >> 4;
    int m0 = blockIdx.y << 7, n0 = blockIdx.x << 7;
    f32x4 acc[4][4] = {};
    int mb = (w & 1) * 64, nb = (w >> 1) * 64;
    int lr = lane >> 2, lc = (lane & 3) << 3;   // async: lane -> row lr, k-chunk lc
    for (int k0 = 0; k0 < 512; k0 += 32) {
#pragma unroll
        for (int i = 0; i < 2; ++i) {
            int r = w * 32 + i * 16;
            async_cp16(X  + (size_t)(m0 + r + lr) * 512 + k0 + lc, &As[r * 32]);
            async_cp16(Wt + (size_t)(n0 + r + lr) * 512 + k0 + lc, &Bs[r * 32]);
        }
        __syncthreads();
        bf16x8 af[4], bf_[4];
#pragma unroll
        for (int mi = 0; mi < 4; ++mi)
            af[mi] = *(const bf16x8*)&As[(mb + mi * 16 + ml) * 32 + q * 8];
#pragma unroll
        for (int ni = 0; ni < 4; ++ni)
            bf_[ni] = *(const bf16x8*)&Bs[(nb + ni * 16 + ml) * 32 + q * 8];
#pragma unroll
        for (int mi = 0; mi < 4; ++mi)
#pragma unroll
            for (int ni = 0; ni < 4; ++ni)
                acc[mi][ni] = __builtin_amdgcn_mfma_f32_16x16x32_bf16(af[mi], bf_[ni], acc[mi][ni], 0, 0, 0);
        __syncthreads();
    }
#pragma unroll
    for (int ni = 0; ni < 4; ++ni) {
        int col = n0 + nb + ni * 16 + ml;
        float bias = bl[col];
#pragma unroll
        for (int mi = 0; mi < 4; ++mi) {
#pragma unroll
            for (int r = 0; r < 4; ++r) {
                int row = m0 + mb + mi * 16 + q * 4 + r;
                Xg[(size_t)row * 2048 + col] = (__bf16)(acc[mi][ni][r] + bias);
            }
        }
    }
}

// ---------------- one LSTM step: zero-LDS MFMA GEMM + fused pointwise ----------------
// Grid (32,4): bx -> j0 = bx*16 h-cols (x4 gates), by -> n0 = by*64 rows.
// split: gates = h@WhhT^T + Xg_t ; fused: gates = x@WihT^T + h@WhhT^T + bl
__global__ __launch_bounds__(256) void k_lstm_step(const __bf16* __restrict__ hin,
                                                   __bf16* __restrict__ hout,
                                                   float* __restrict__ cbuf,
                                                   const __bf16* __restrict__ Xt,
                                                   const __bf16* __restrict__ WihT,
                                                   const __bf16* __restrict__ Xg_t,
                                                   const __bf16* __restrict__ WhhT,
                                                   const float* __restrict__ bl,
                                                   float* __restrict__ out,
                                                   int t, int fused)
{
    int tid = threadIdx.x;
    int w = tid >> 6, lane = tid & 63;
    int ml = lane & 15, q = lane >> 4;
    int n0 = blockIdx.y << 6;
    int j0 = blockIdx.x << 4;
    f32x4 acc[4] = {};
    const __bf16* Arow = hin + (size_t)(n0 + w * 16 + ml) * 512 + q * 8;
    const __bf16* B0   = WhhT + (size_t)(j0 + ml) * 512 + q * 8;   // gate g at +g*512*512
#pragma unroll 4
    for (int k0 = 0; k0 < 512; k0 += 32) {
        bf16x8 a = *(const bf16x8*)(Arow + k0);
#pragma unroll
        for (int g = 0; g < 4; ++g) {
            bf16x8 b = *(const bf16x8*)(B0 + ((size_t)g << 18) + k0);
            acc[g] = __builtin_amdgcn_mfma_f32_16x16x32_bf16(a, b, acc[g], 0, 0, 0);
        }
    }
    if (fused) {
        const __bf16* A2 = Xt + (size_t)(n0 + w * 16 + ml) * 512 + q * 8;
        const __bf16* B2 = WihT + (size_t)(j0 + ml) * 512 + q * 8;
#pragma unroll 4
        for (int k0 = 0; k0 < 512; k0 += 32) {
            bf16x8 a = *(const bf16x8*)(A2 + k0);
#pragma unroll
            for (int g = 0; g < 4; ++g) {
                bf16x8 b = *(const bf16x8*)(B2 + ((size_t)g << 18) + k0);
                acc[g] = __builtin_amdgcn_mfma_f32_16x16x32_bf16(a, b, acc[g], 0, 0, 0);
            }
        }
    }
    int jc = j0 + ml;
#pragma unroll
    for (int r = 0; r < 4; ++r) {
        int n = n0 + w * 16 + q * 4 + r;
        int b = n >> 5, u = n & 31;
        int s = u * 64 + t;
        float pi, pf, pg, po;
        if (fused) {
            pi = acc[0][r] + bl[jc];
            pf = acc[1][r] + bl[512 + jc];
            pg = acc[2][r] + bl[1024 + jc];
            po = acc[3][r] + bl[1536 + jc];
        } else {
            const __bf16* xg = Xg_t + (size_t)n * 2048;
            pi = acc[0][r] + (float)xg[jc];
            pf = acc[1][r] + (float)xg[512 + jc];
            pg = acc[2][r] + (float)xg[1024 + jc];
            po = acc[3][r] + (float)xg[1536 + jc];
        }
        float ig = sigm(pi), fg = sigm(pf);
        float gg = tanhf(pg), og = sigm(po);
        float cn = fg * cbuf[n * 512 + jc] + ig * gg;
        cbuf[n * 512 + jc] = cn;
        float hn = og * tanhf(cn);
        hout[n * 512 + jc] = (__bf16)hn;
        out[OFF_MB + ((size_t)s * 8 + b) * 512 + jc] = hn;   // memory_bank[s][b][jc]
    }
}

// ---------------- nodes: utt_h + global mean node ----------------
__global__ __launch_bounds__(256) void k_nodes(const __bf16* __restrict__ hT,
                                               float* __restrict__ nodes)
{
    int b = blockIdx.x;
    for (int k = threadIdx.x; k < 512; k += 256) {
        float sum = 0.f;
        for (int u = 0; u < 32; ++u) {
            float v = (float)hT[(b * 32 + u) * 512 + k];
            nodes[(b * 33 + u) * 512 + k] = v;
            sum += v;
        }
        nodes[(b * 33 + 32) * 512 + k] = sum * (1.0f / 32.0f);
    }
}

// ---------------- edges: msg = x_src @ W_rel[r], scatter-add to agg[dst] ----------------
__global__ __launch_bounds__(256) void k_edges(const float* __restrict__ nodes,
                                               const int* __restrict__ edge_src,
                                               const int* __restrict__ edge_dst,
                                               const int* __restrict__ rels,
                                               const float* __restrict__ Wrel,
                                               float* __restrict__ agg)
{
    __shared__ float xs[512];
    int eg = blockIdx.x;                 // B*E = 1024 blocks
    int b = eg >> 7, e = eg & 127;
    int es = edge_src[b * 128 + e];
    int ed = edge_dst[b * 128 + e];
    int r  = rels[b * 128 + e];
    int tid = threadIdx.x;
    for (int k = tid; k < 512; k += 256) xs[k] = nodes[(b * 33 + es) * 512 + k];
    __syncthreads();
    const float* Wr = Wrel + r * 262144;
    float a0 = 0.f, a1 = 0.f;
#pragma unroll 4
    for (int k = 0; k < 512; ++k) {
        float xk = xs[k];
        a0 += xk * Wr[k * 512 + tid];
        a1 += xk * Wr[k * 512 + 256 + tid];
    }
    atomicAdd(&agg[(b * 33 + ed) * 512 + tid], a0);
    atomicAdd(&agg[(b * 33 + ed) * 512 + 256 + tid], a1);
}

// ---------------- GNN gate fusion per node ----------------
__global__ __launch_bounds__(256) void k_gnn(const float* __restrict__ nodes,
                                             const float* __restrict__ agg,
                                             const float* __restrict__ Wself,
                                             const float* __restrict__ bgnn,
                                             const float* __restrict__ Wg1,
                                             const float* __restrict__ Wg2,
                                             float* __restrict__ newn,
                                             float* __restrict__ out)
{
    __shared__ float nd[512], ag[512];
    int vg = blockIdx.x;                 // B*33 = 264 blocks
    int b = vg / 33, v = vg % 33;
    int tid = threadIdx.x;
    for (int k = tid; k < 512; k += 256) {
        nd[k] = nodes[vg * 512 + k];
        ag[k] = agg[vg * 512 + k];
    }
    __syncthreads();
#pragma unroll
    for (int half = 0; half < 2; ++half) {
        int jj = tid + half * 256;
        float a_s = 0.f, a1 = 0.f, a2 = 0.f;
#pragma unroll 4
        for (int k = 0; k < 512; ++k) {
            float ndk = nd[k], agk = ag[k];
            a_s += ndk * Wself[k * 512 + jj];
            a1  += ndk * Wg1[k * 512 + jj];
            a2  += agk * Wg2[k * 512 + jj];
        }
        float outv = a_s + ag[jj] + bgnn[jj];
        outv = fmaxf(outv, 0.f);
        float gate = sigm(a1 + a2);
        float newv = gate * outv + (1.f - gate) * nd[jj];
        newn[vg * 512 + jj] = newv;
        if (v == 32) {                   // global_reps -> enc_h, enc_c
            out[OFF_ENCH + b * 512 + jj] = newv;
            out[OFF_ENCC + b * 512 + jj] = newv;
        }
    }
}

// ---------------- mbu: broadcast utt_upd over L into (S,B,H) ----------------
__global__ __launch_bounds__(256) void k_mbu(const float* __restrict__ newn,
                                             float* __restrict__ out)
{
    int idx = blockIdx.x * 256 + threadIdx.x;   // S*B*H/8 = 1048576 threads
    int k8 = (idx & 63) << 3;
    int rest = idx >> 6;
    int b = rest & 7;
    int s = rest >> 3;
    int u = s >> 6;
    const float* sp = &newn[(b * 33 + u) * 512 + k8];
    f32x4 v0 = *(const f32x4*)sp;
    f32x4 v1 = *(const f32x4*)(sp + 4);
    float* dp = &out[OFF_MBU + (s * 8 + b) * 512 + k8];
    *(f32x4*)dp = v0;
    *(f32x4*)(dp + 4) = v1;
}

extern "C" void kernel_launch(void* const* d_in, const int* in_sizes, int n_in,
                              void* d_out, int out_size, void* d_ws, size_t ws_size,
                              hipStream_t stream)
{
    (void)in_sizes; (void)n_in; (void)out_size;
    const int*   src      = (const int*)d_in[0];
    const int*   speaker  = (const int*)d_in[2];
    const int*   lengths  = (const int*)d_in[3];
    const int*   edge_src = (const int*)d_in[4];
    const int*   edge_dst = (const int*)d_in[5];
    const int*   rels     = (const int*)d_in[6];
    const float* emb   = (const float*)d_in[7];
    const float* spk   = (const float*)d_in[8];
    const float* Wih   = (const float*)d_in[9];
    const float* Whh   = (const float*)d_in[10];
    const float* bl    = (const float*)d_in[11];
    const float* Wrel  = (const float*)d_in[12];
    const float* Wself = (const float*)d_in[13];
    const float* bgnn  = (const float*)d_in[14];
    const float* Wg1   = (const float*)d_in[15];
    const float* Wg2   = (const float*)d_in[16];
    float* out = (float*)d_out;
    char*  ws  = (char*)d_ws;

    __bf16* X     = (__bf16*)(ws + WS_X);
    __bf16* WihT  = (__bf16*)(ws + WS_WIH);
    __bf16* WhhT  = (__bf16*)(ws + WS_WHH);
    __bf16* hb0   = (__bf16*)(ws + WS_HBUF);
    __bf16* hb1   = hb0 + 131072;
    float*  cbuf  = (float*)(ws + WS_CBUF);
    float*  nodes = (float*)(ws + WS_NODES);
    float*  agg   = (float*)(ws + WS_AGG);
    float*  newn  = (float*)(ws + WS_NEWN);
    __bf16* Xg    = (__bf16*)(ws + WS_XG);

    int split = (ws_size >= WS_SPLIT_NEED) ? 1 : 0;

    k_init<<<2145, 256, 0, stream>>>((unsigned int*)(ws + WS_HBUF), lengths, out);
    k_cvtw<<<512, 256, 0, stream>>>(Wih, Whh, WihT, WhhT);
    k_embed<<<4096, 256, 0, stream>>>(src, speaker, emb, spk, X);
    if (split)
        k_gemm_xg<<<dim3(16, 128), 256, 0, stream>>>(X, WihT, bl, Xg);
    for (int t = 0; t < 64; ++t) {
        const __bf16* hin = (t & 1) ? hb1 : hb0;
        __bf16* hout      = (t & 1) ? hb0 : hb1;
        k_lstm_step<<<dim3(32, 4), 256, 0, stream>>>(
            hin, hout, cbuf,
            X + (size_t)t * 131072, WihT,
            Xg + (size_t)t * 524288, WhhT, bl,
            out, t, split ? 0 : 1);
    }
    k_nodes<<<8, 256, 0, stream>>>(hb0, nodes);   // after 64 steps, hT lives in hb0
    k_edges<<<1024, 256, 0, stream>>>(nodes, edge_src, edge_dst, rels, Wrel, agg);
    k_gnn<<<264, 256, 0, stream>>>(nodes, agg, Wself, bgnn, Wg1, Wg2, newn, out);
    k_mbu<<<4096, 256, 0, stream>>>(newn, out);
}

// Round 4
// 980.368 us; speedup vs baseline: 2.4562x; 1.3791x over previous
//
#include <hip/hip_runtime.h>
#include <hip/hip_bf16.h>
#include <math.h>

typedef __bf16 bf16x8 __attribute__((ext_vector_type(8)));
typedef float  f32x4  __attribute__((ext_vector_type(4)));

// Problem dims: B=8, U=32, L=64, H=512, V=32000, NSPK=16, R=4, E=128, S=2048
// N = B*U = 256 sequences, 4H = 2048 gate cols. All float I/O is fp32.

// Output element offsets (fp32 elements), flat order:
// enc_h, enc_c, memory_bank(S,B,H), lengths, mbu(S,B,H), lengths, hier(B,S)
#define OFF_ENCH 0
#define OFF_ENCC 4096
#define OFF_MB   8192
#define OFF_LEN1 8396800
#define OFF_MBU  8396808
#define OFF_LEN2 16785416
#define OFF_HIER 16785424

// Workspace byte offsets
#define WS_X     0          // X bf16: 16384*512*2 = 16777216
#define WS_WIH   16777216   // WihT bf16 [2048][512]: 2097152
#define WS_WHH   18874368   // WhhT bf16 [2048][512]: 2097152
#define WS_HBUF  20971520   // 2*256*512*2 = 524288
#define WS_CBUF  21495808   // 256*512*4   = 524288
#define WS_NODES 22020096   // 8*33*512*4  = 540672
#define WS_AGG   22560768   // 540672
#define WS_NEWN  23101440   // 540672 -> ends 23642112
#define WS_XG    23642112   // Xg bf16: 16384*2048*2 = 67108864 -> ends 90750976
#define WS_SPLIT_NEED 90750976ull
#define ZERO_WORDS 532480   // WS_HBUF..WS_AGG end (h bufs, c, nodes, agg) in u32

__device__ __forceinline__ float sigm(float x) { return 1.0f / (1.0f + expf(-x)); }

__device__ __forceinline__ void async_cp16(const __bf16* g, __bf16* l) {
    __builtin_amdgcn_global_load_lds((const __attribute__((address_space(1))) void*)g,
                                     (__attribute__((address_space(3))) void*)l,
                                     16, 0, 0);
}

// ---------------- init: zero state + constant outputs ----------------
__global__ __launch_bounds__(256) void k_init(unsigned int* zero_base,
                                              const int* lengths, float* out)
{
    int idx = blockIdx.x * 256 + threadIdx.x;
    if (idx < ZERO_WORDS) { zero_base[idx] = 0u; return; }
    int j = idx - ZERO_WORDS;
    if (j < 16384) { out[OFF_HIER + j] = 64.0f; return; }  // hier_matrix = L
    int j2 = j - 16384;
    if (j2 < 16) {
        float v = (float)lengths[j2 & 7];
        out[(j2 < 8 ? OFF_LEN1 : OFF_LEN2) + (j2 & 7)] = v;
    }
}

// ---------------- W_ih / W_hh fp32 [512][2048] -> bf16 transposed [2048][512] ----------------
__global__ __launch_bounds__(256) void k_cvtw(const float* __restrict__ Wih,
                                              const float* __restrict__ Whh,
                                              __bf16* __restrict__ WihT,
                                              __bf16* __restrict__ WhhT)
{
    __shared__ float tile[64][65];
    int gid = blockIdx.x;                         // 512 blocks: 2 mats x 8 k x 32 c
    const float* Wsrc = (gid >> 8) ? Whh : Wih;
    __bf16*      Wdst = (gid >> 8) ? WhhT : WihT;
    int rem = gid & 255;
    int k0 = (rem >> 5) << 6;
    int c0 = (rem & 31) << 6;
    int tid = threadIdx.x;
#pragma unroll
    for (int i = 0; i < 16; ++i) {
        int idx = tid + i * 256;
        int kl = idx >> 6, cl = idx & 63;
        tile[cl][kl] = Wsrc[(size_t)(k0 + kl) * 2048 + c0 + cl];
    }
    __syncthreads();
#pragma unroll
    for (int i = 0; i < 16; ++i) {
        int idx = tid + i * 256;
        int cl = idx >> 6, kl = idx & 63;
        Wdst[(size_t)(c0 + cl) * 512 + k0 + kl] = (__bf16)tile[cl][kl];
    }
}

// ---------------- embedding: X[t*256+n][k] = emb[word] + spk[spkid] (bf16) ----------------
__global__ __launch_bounds__(256) void k_embed(const int* __restrict__ src,
                                               const int* __restrict__ speaker,
                                               const float* __restrict__ emb,
                                               const float* __restrict__ spk,
                                               __bf16* __restrict__ X)
{
    int tid = blockIdx.x * 256 + threadIdx.x;   // 16384*64 threads
    int p  = tid >> 6;                          // t*256 + n
    int k8 = (tid & 63) << 3;
    int t = p >> 8, n = p & 255;
    int b = n >> 5, u = n & 31;
    int s = u * 64 + t;
    int word = src[s * 8 + b];                  // src (S,B,1)
    int sid  = speaker[b * 2048 + s];           // speaker (B,S)
    f32x4 e0 = *(const f32x4*)&emb[word * 512 + k8];
    f32x4 e1 = *(const f32x4*)&emb[word * 512 + k8 + 4];
    f32x4 s0 = *(const f32x4*)&spk[sid * 512 + k8];
    f32x4 s1 = *(const f32x4*)&spk[sid * 512 + k8 + 4];
    bf16x8 o;
#pragma unroll
    for (int j = 0; j < 4; ++j) {
        o[j]     = (__bf16)(e0[j] + s0[j]);
        o[4 + j] = (__bf16)(e1[j] + s1[j]);
    }
    *(bf16x8*)&X[p * 512 + k8] = o;
}

// ---------------- Xg = X @ W_ih + b (M=16384,K=512,N=2048), m97-style 128x128 ----------------
__global__ __launch_bounds__(256) void k_gemm_xg(const __bf16* __restrict__ X,
                                                 const __bf16* __restrict__ Wt,
                                                 const float* __restrict__ bl,
                                                 __bf16* __restrict__ Xg)
{
    __shared__ __bf16 As[128 * 32];   // [row][k] stride 32, lane-contiguous for async cp
    __shared__ __bf16 Bs[128 * 32];   // [col][k] stride 32
    int tid = threadIdx.x;
    int w = tid >> 6, lane = tid & 63;
    int ml = lane & 15, q = lane >> 4;
    int m0 = blockIdx.y << 7, n0 = blockIdx.x << 7;
    f32x4 acc[4][4] = {};
    int mb = (w & 1) * 64, nb = (w >> 1) * 64;
    int lr = lane >> 2, lc = (lane & 3) << 3;   // async: lane -> row lr, k-chunk lc
    for (int k0 = 0; k0 < 512; k0 += 32) {
#pragma unroll
        for (int i = 0; i < 2; ++i) {
            int r = w * 32 + i * 16;
            async_cp16(X  + (size_t)(m0 + r + lr) * 512 + k0 + lc, &As[r * 32]);
            async_cp16(Wt + (size_t)(n0 + r + lr) * 512 + k0 + lc, &Bs[r * 32]);
        }
        __syncthreads();
        bf16x8 af[4], bf_[4];
#pragma unroll
        for (int mi = 0; mi < 4; ++mi)
            af[mi] = *(const bf16x8*)&As[(mb + mi * 16 + ml) * 32 + q * 8];
#pragma unroll
        for (int ni = 0; ni < 4; ++ni)
            bf_[ni] = *(const bf16x8*)&Bs[(nb + ni * 16 + ml) * 32 + q * 8];
#pragma unroll
        for (int mi = 0; mi < 4; ++mi)
#pragma unroll
            for (int ni = 0; ni < 4; ++ni)
                acc[mi][ni] = __builtin_amdgcn_mfma_f32_16x16x32_bf16(af[mi], bf_[ni], acc[mi][ni], 0, 0, 0);
        __syncthreads();
    }
#pragma unroll
    for (int ni = 0; ni < 4; ++ni) {
        int col = n0 + nb + ni * 16 + ml;
        float bias = bl[col];
#pragma unroll
        for (int mi = 0; mi < 4; ++mi) {
#pragma unroll
            for (int r = 0; r < 4; ++r) {
                int row = m0 + mb + mi * 16 + q * 4 + r;
                Xg[(size_t)row * 2048 + col] = (__bf16)(acc[mi][ni][r] + bias);
            }
        }
    }
}

// ---------------- one LSTM step: zero-LDS MFMA GEMM, 256 blocks, wave K-split ----------------
// Grid (32,8): bx -> j0 = bx*16 h-cols (x4 gates), by -> n0 = by*32 rows.
// 4 waves: rh = w&1 (row half of 16), kh = w>>1 (K half). LDS reduce across kh.
__global__ __launch_bounds__(256) void k_lstm_step(const __bf16* __restrict__ hin,
                                                   __bf16* __restrict__ hout,
                                                   float* __restrict__ cbuf,
                                                   const __bf16* __restrict__ Xt,
                                                   const __bf16* __restrict__ WihT,
                                                   const __bf16* __restrict__ Xg_t,
                                                   const __bf16* __restrict__ WhhT,
                                                   const float* __restrict__ bl,
                                                   float* __restrict__ out,
                                                   int t, int fused)
{
    __shared__ float red[2][64][17];
    int tid = threadIdx.x;
    int w = tid >> 6, lane = tid & 63;
    int ml = lane & 15, q = lane >> 4;
    int rh = w & 1, kh = w >> 1;
    int n0 = blockIdx.y << 5;
    int j0 = blockIdx.x << 4;
    f32x4 acc[4] = {};
    const __bf16* Arow = hin + (size_t)(n0 + rh * 16 + ml) * 512 + kh * 256 + q * 8;
    const __bf16* B0   = WhhT + (size_t)(j0 + ml) * 512 + kh * 256 + q * 8;  // +g*512*512
#pragma unroll
    for (int k0 = 0; k0 < 256; k0 += 32) {
        bf16x8 a = *(const bf16x8*)(Arow + k0);
#pragma unroll
        for (int g = 0; g < 4; ++g) {
            bf16x8 b = *(const bf16x8*)(B0 + ((size_t)g << 18) + k0);
            acc[g] = __builtin_amdgcn_mfma_f32_16x16x32_bf16(a, b, acc[g], 0, 0, 0);
        }
    }
    if (fused) {
        const __bf16* A2 = Xt + (size_t)(n0 + rh * 16 + ml) * 512 + kh * 256 + q * 8;
        const __bf16* B2 = WihT + (size_t)(j0 + ml) * 512 + kh * 256 + q * 8;
#pragma unroll
        for (int k0 = 0; k0 < 256; k0 += 32) {
            bf16x8 a = *(const bf16x8*)(A2 + k0);
#pragma unroll
            for (int g = 0; g < 4; ++g) {
                bf16x8 b = *(const bf16x8*)(B2 + ((size_t)g << 18) + k0);
                acc[g] = __builtin_amdgcn_mfma_f32_16x16x32_bf16(a, b, acc[g], 0, 0, 0);
            }
        }
    }
    if (kh == 1) {
#pragma unroll
        for (int g = 0; g < 4; ++g)
#pragma unroll
            for (int r = 0; r < 4; ++r)
                red[rh][lane][g * 4 + r] = acc[g][r];
    }
    __syncthreads();
    if (kh == 1) return;
#pragma unroll
    for (int g = 0; g < 4; ++g)
#pragma unroll
        for (int r = 0; r < 4; ++r)
            acc[g][r] += red[rh][lane][g * 4 + r];

    int jc = j0 + ml;
#pragma unroll
    for (int r = 0; r < 4; ++r) {
        int n = n0 + rh * 16 + q * 4 + r;
        int b = n >> 5, u = n & 31;
        int s = u * 64 + t;
        float pi, pf, pg, po;
        if (fused) {
            pi = acc[0][r] + bl[jc];
            pf = acc[1][r] + bl[512 + jc];
            pg = acc[2][r] + bl[1024 + jc];
            po = acc[3][r] + bl[1536 + jc];
        } else {
            const __bf16* xg = Xg_t + (size_t)n * 2048;
            pi = acc[0][r] + (float)xg[jc];
            pf = acc[1][r] + (float)xg[512 + jc];
            pg = acc[2][r] + (float)xg[1024 + jc];
            po = acc[3][r] + (float)xg[1536 + jc];
        }
        float ig = sigm(pi), fg = sigm(pf);
        float gg = tanhf(pg), og = sigm(po);
        float cn = fg * cbuf[n * 512 + jc] + ig * gg;
        cbuf[n * 512 + jc] = cn;
        float hn = og * tanhf(cn);
        hout[n * 512 + jc] = (__bf16)hn;
        out[OFF_MB + ((size_t)s * 8 + b) * 512 + jc] = hn;   // memory_bank[s][b][jc]
    }
}

// ---------------- nodes: utt_h + global mean node ----------------
__global__ __launch_bounds__(256) void k_nodes(const __bf16* __restrict__ hT,
                                               float* __restrict__ nodes)
{
    int b = blockIdx.x;
    for (int k = threadIdx.x; k < 512; k += 256) {
        float sum = 0.f;
        for (int u = 0; u < 32; ++u) {
            float v = (float)hT[(b * 32 + u) * 512 + k];
            nodes[(b * 33 + u) * 512 + k] = v;
            sum += v;
        }
        nodes[(b * 33 + 32) * 512 + k] = sum * (1.0f / 32.0f);
    }
}

// ---------------- edges: msg = x_src @ W_rel[r], scatter-add to agg[dst] ----------------
__global__ __launch_bounds__(256) void k_edges(const float* __restrict__ nodes,
                                               const int* __restrict__ edge_src,
                                               const int* __restrict__ edge_dst,
                                               const int* __restrict__ rels,
                                               const float* __restrict__ Wrel,
                                               float* __restrict__ agg)
{
    __shared__ float xs[512];
    int eg = blockIdx.x;                 // B*E = 1024 blocks
    int b = eg >> 7, e = eg & 127;
    int es = edge_src[b * 128 + e];
    int ed = edge_dst[b * 128 + e];
    int r  = rels[b * 128 + e];
    int tid = threadIdx.x;
    for (int k = tid; k < 512; k += 256) xs[k] = nodes[(b * 33 + es) * 512 + k];
    __syncthreads();
    const float* Wr = Wrel + r * 262144;
    float a0 = 0.f, a1 = 0.f;
#pragma unroll 4
    for (int k = 0; k < 512; ++k) {
        float xk = xs[k];
        a0 += xk * Wr[k * 512 + tid];
        a1 += xk * Wr[k * 512 + 256 + tid];
    }
    atomicAdd(&agg[(b * 33 + ed) * 512 + tid], a0);
    atomicAdd(&agg[(b * 33 + ed) * 512 + 256 + tid], a1);
}

// ---------------- GNN gate fusion: grid (264 nodes, 8 j-tiles), in-block K-split ----------------
__global__ __launch_bounds__(256) void k_gnn(const float* __restrict__ nodes,
                                             const float* __restrict__ agg,
                                             const float* __restrict__ Wself,
                                             const float* __restrict__ bgnn,
                                             const float* __restrict__ Wg1,
                                             const float* __restrict__ Wg2,
                                             float* __restrict__ newn,
                                             float* __restrict__ out)
{
    __shared__ float nd[512], ag[512];
    __shared__ float red[4][3][64];
    int vg = blockIdx.x;                 // 0..263
    int j0 = blockIdx.y << 6;            // 8 tiles of 64 cols
    int b = vg / 33, v = vg % 33;
    int tid = threadIdx.x;
    for (int k = tid; k < 512; k += 256) {
        nd[k] = nodes[vg * 512 + k];
        ag[k] = agg[vg * 512 + k];
    }
    __syncthreads();
    int jl = tid & 63, kq = tid >> 6;
    int jj = j0 + jl;
    int kbase = kq << 7;                 // 128-k slice per quarter
    float a_s = 0.f, a1 = 0.f, a2 = 0.f;
#pragma unroll 4
    for (int kk = 0; kk < 128; ++kk) {
        int k = kbase + kk;
        float ndk = nd[k], agk = ag[k];
        a_s += ndk * Wself[k * 512 + jj];
        a1  += ndk * Wg1[k * 512 + jj];
        a2  += agk * Wg2[k * 512 + jj];
    }
    red[kq][0][jl] = a_s;
    red[kq][1][jl] = a1;
    red[kq][2][jl] = a2;
    __syncthreads();
    if (tid < 64) {
        int j = j0 + tid;
        float s0 = red[0][0][tid] + red[1][0][tid] + red[2][0][tid] + red[3][0][tid];
        float s1 = red[0][1][tid] + red[1][1][tid] + red[2][1][tid] + red[3][1][tid];
        float s2 = red[0][2][tid] + red[1][2][tid] + red[2][2][tid] + red[3][2][tid];
        float outv = fmaxf(s0 + ag[j] + bgnn[j], 0.f);
        float gate = sigm(s1 + s2);
        float newv = gate * outv + (1.f - gate) * nd[j];
        newn[vg * 512 + j] = newv;
        if (v == 32) {                   // global_reps -> enc_h, enc_c
            out[OFF_ENCH + b * 512 + j] = newv;
            out[OFF_ENCC + b * 512 + j] = newv;
        }
    }
}

// ---------------- mbu: broadcast utt_upd over L into (S,B,H) ----------------
__global__ __launch_bounds__(256) void k_mbu(const float* __restrict__ newn,
                                             float* __restrict__ out)
{
    int idx = blockIdx.x * 256 + threadIdx.x;   // S*B*H/8 = 1048576 threads
    int k8 = (idx & 63) << 3;
    int rest = idx >> 6;
    int b = rest & 7;
    int s = rest >> 3;
    int u = s >> 6;
    const float* sp = &newn[(b * 33 + u) * 512 + k8];
    f32x4 v0 = *(const f32x4*)sp;
    f32x4 v1 = *(const f32x4*)(sp + 4);
    float* dp = &out[OFF_MBU + (s * 8 + b) * 512 + k8];
    *(f32x4*)dp = v0;
    *(f32x4*)(dp + 4) = v1;
}

extern "C" void kernel_launch(void* const* d_in, const int* in_sizes, int n_in,
                              void* d_out, int out_size, void* d_ws, size_t ws_size,
                              hipStream_t stream)
{
    (void)in_sizes; (void)n_in; (void)out_size;
    const int*   src      = (const int*)d_in[0];
    const int*   speaker  = (const int*)d_in[2];
    const int*   lengths  = (const int*)d_in[3];
    const int*   edge_src = (const int*)d_in[4];
    const int*   edge_dst = (const int*)d_in[5];
    const int*   rels     = (const int*)d_in[6];
    const float* emb   = (const float*)d_in[7];
    const float* spk   = (const float*)d_in[8];
    const float* Wih   = (const float*)d_in[9];
    const float* Whh   = (const float*)d_in[10];
    const float* bl    = (const float*)d_in[11];
    const float* Wrel  = (const float*)d_in[12];
    const float* Wself = (const float*)d_in[13];
    const float* bgnn  = (const float*)d_in[14];
    const float* Wg1   = (const float*)d_in[15];
    const float* Wg2   = (const float*)d_in[16];
    float* out = (float*)d_out;
    char*  ws  = (char*)d_ws;

    __bf16* X     = (__bf16*)(ws + WS_X);
    __bf16* WihT  = (__bf16*)(ws + WS_WIH);
    __bf16* WhhT  = (__bf16*)(ws + WS_WHH);
    __bf16* hb0   = (__bf16*)(ws + WS_HBUF);
    __bf16* hb1   = hb0 + 131072;
    float*  cbuf  = (float*)(ws + WS_CBUF);
    float*  nodes = (float*)(ws + WS_NODES);
    float*  agg   = (float*)(ws + WS_AGG);
    float*  newn  = (float*)(ws + WS_NEWN);
    __bf16* Xg    = (__bf16*)(ws + WS_XG);

    int split = (ws_size >= WS_SPLIT_NEED) ? 1 : 0;

    k_init<<<2145, 256, 0, stream>>>((unsigned int*)(ws + WS_HBUF), lengths, out);
    k_cvtw<<<512, 256, 0, stream>>>(Wih, Whh, WihT, WhhT);
    k_embed<<<4096, 256, 0, stream>>>(src, speaker, emb, spk, X);
    if (split)
        k_gemm_xg<<<dim3(16, 128), 256, 0, stream>>>(X, WihT, bl, Xg);
    for (int t = 0; t < 64; ++t) {
        const __bf16* hin = (t & 1) ? hb1 : hb0;
        __bf16* hout      = (t & 1) ? hb0 : hb1;
        k_lstm_step<<<dim3(32, 8), 256, 0, stream>>>(
            hin, hout, cbuf,
            X + (size_t)t * 131072, WihT,
            Xg + (size_t)t * 524288, WhhT, bl,
            out, t, split ? 0 : 1);
    }
    k_nodes<<<8, 256, 0, stream>>>(hb0, nodes);   // after 64 steps, hT lives in hb0
    k_edges<<<1024, 256, 0, stream>>>(nodes, edge_src, edge_dst, rels, Wrel, agg);
    k_gnn<<<dim3(264, 8), 256, 0, stream>>>(nodes, agg, Wself, bgnn, Wg1, Wg2, newn, out);
    k_mbu<<<4096, 256, 0, stream>>>(newn, out);
}